// Round 1
// 399.360 us; speedup vs baseline: 1.0978x; 1.0978x over previous
//
#include <hip/hip_runtime.h>

// CFConv, round 5. Fused scatter-reduce:
//  - edges processed in dst-sorted order (gather rbf via eperm)
//  - per-thread segmented scan over its 32 sorted rows + fp32 atomicAdd
//    flushes (~5/tile) -> msg buffer + segment_reduce kernel eliminated
//    (saves ~328 MB of HBM round-trip)
//  - LDS: sT overlaps sHv (hv read hoisted before GEMM1) -> 34.8 KB/block,
//    4 blocks/CU instead of 3
//  - fp32 message accumulation (no bf16 msg quantization anymore)

#define N_NODES 40000
#define N_EDGES 640000
#define IN_CH 128
#define OUT_CH 128
#define NUM_RBF 64

#define TILE_M 64
#define NTILES (N_EDGES / TILE_M)  // 10000 exact
#define RBF_STR 72   // ushorts
#define T_STR 136    // ushorts
#define HV_STR 136   // ushorts
#define W1_STR 72
#define W2_STR 136
#define NSCB ((N_NODES + 255) / 256)  // 157 scan blocks
#define EDGE_GRID 1024               // 4 blocks/CU x 256 CUs, persistent

typedef __attribute__((ext_vector_type(8))) short bf16x8;
typedef __attribute__((ext_vector_type(16))) float f32x16;

__device__ __forceinline__ unsigned short f2bf(float f) {
  unsigned u = __float_as_uint(f);
  return (unsigned short)((u + 0x7FFFu + ((u >> 16) & 1u)) >> 16);
}
__device__ __forceinline__ float bf2f(unsigned short s) {
  return __uint_as_float(((unsigned)s) << 16);
}

// ---------------------------------------------------------------------------
// h = bf16(x @ Wl + bl)
// ---------------------------------------------------------------------------
__global__ __launch_bounds__(256) void node_linear_mfma(
    const float* __restrict__ x, const float* __restrict__ Wl,
    const float* __restrict__ bl, unsigned short* __restrict__ hbf) {
  __shared__ __align__(16) char pool[IN_CH * W2_STR * 2];  // 34816 B
  const int t = threadIdx.x;
  const int lane = t & 63;
  const int l31 = lane & 31;
  const int lhalf = lane >> 5;
  const int wv = t >> 6;

  {
    unsigned short* sWT = (unsigned short*)pool;
    const int k2 = t >> 1;
    const int d0 = (t & 1) * 64;
#pragma unroll
    for (int i = 0; i < 16; ++i) {
      float4 v = *(const float4*)(Wl + k2 * OUT_CH + d0 + 4 * i);
      sWT[(d0 + 4 * i + 0) * W2_STR + k2] = f2bf(v.x);
      sWT[(d0 + 4 * i + 1) * W2_STR + k2] = f2bf(v.y);
      sWT[(d0 + 4 * i + 2) * W2_STR + k2] = f2bf(v.z);
      sWT[(d0 + 4 * i + 3) * W2_STR + k2] = f2bf(v.w);
    }
  }
  __syncthreads();
  const int nbase = wv * 32 + l31;
  bf16x8 BW[8];
  {
    const unsigned short* sWT = (const unsigned short*)pool;
#pragma unroll
    for (int kk = 0; kk < 8; ++kk)
      BW[kk] = *(const bf16x8*)&sWT[nbase * W2_STR + kk * 16 + lhalf * 8];
  }
  const float blv = bl[nbase];
  __syncthreads();

  const int rbase = blockIdx.x * TILE_M;
  unsigned short* sX = (unsigned short*)pool;
  {
    const int m = t >> 2;
    const int c0 = (t & 3) * 32;
    const float* src = x + (size_t)(rbase + m) * IN_CH + c0;
#pragma unroll
    for (int i = 0; i < 8; ++i) {
      float4 v = *(const float4*)(src + 4 * i);
      ushort4 p;
      p.x = f2bf(v.x); p.y = f2bf(v.y); p.z = f2bf(v.z); p.w = f2bf(v.w);
      *(ushort4*)&sX[m * T_STR + c0 + 4 * i] = p;
    }
  }
  __syncthreads();
#pragma unroll
  for (int mt = 0; mt < 2; ++mt) {
    f32x16 acc = {0.f, 0.f, 0.f, 0.f, 0.f, 0.f, 0.f, 0.f,
                  0.f, 0.f, 0.f, 0.f, 0.f, 0.f, 0.f, 0.f};
#pragma unroll
    for (int kk = 0; kk < 8; ++kk) {
      bf16x8 A = *(const bf16x8*)&sX[(mt * 32 + l31) * T_STR + kk * 16 + lhalf * 8];
      acc = __builtin_amdgcn_mfma_f32_32x32x16_bf16(A, BW[kk], acc, 0, 0, 0);
    }
#pragma unroll
    for (int r = 0; r < 16; ++r) {
      const int rowm = mt * 32 + (r & 3) + 8 * (r >> 2) + 4 * lhalf;
      hbf[(size_t)(rbase + rowm) * OUT_CH + nbase] = f2bf(acc[r] + blv);
    }
  }
}

// ---------------------------------------------------------------------------
// counting sort by dst (hist + hierarchical scan + scatter)
// ---------------------------------------------------------------------------
__global__ void hist_kernel(const int* __restrict__ rowI, int* __restrict__ count) {
  int e = blockIdx.x * 256 + threadIdx.x;
  if (e < N_EDGES) atomicAdd(&count[rowI[e]], 1);
}

__global__ __launch_bounds__(256) void scan1_kernel(const int* __restrict__ count,
                                                    int* __restrict__ tscan,
                                                    int* __restrict__ bsum) {
  __shared__ int s[256];
  const int t = threadIdx.x;
  const int i = blockIdx.x * 256 + t;
  const int v = (i < N_NODES) ? count[i] : 0;
  s[t] = v;
  __syncthreads();
  for (int off = 1; off < 256; off <<= 1) {
    int u = (t >= off) ? s[t - off] : 0;
    __syncthreads();
    s[t] += u;
    __syncthreads();
  }
  if (i < N_NODES) tscan[i] = s[t];
  if (t == 255) bsum[blockIdx.x] = s[255];
}

__global__ __launch_bounds__(256) void scan2_kernel(const int* __restrict__ bsum,
                                                    int* __restrict__ boff) {
  __shared__ int s[256];
  const int t = threadIdx.x;
  const int v = (t < NSCB) ? bsum[t] : 0;
  s[t] = v;
  __syncthreads();
  for (int off = 1; off < 256; off <<= 1) {
    int u = (t >= off) ? s[t - off] : 0;
    __syncthreads();
    s[t] += u;
    __syncthreads();
  }
  if (t < NSCB) boff[t] = s[t] - v;  // exclusive
}

__global__ __launch_bounds__(256) void scan3_kernel(
    const int* __restrict__ count, const int* __restrict__ tscan,
    const int* __restrict__ boff, int* __restrict__ cursor) {
  const int i = blockIdx.x * 256 + threadIdx.x;
  if (i < N_NODES) cursor[i] = boff[blockIdx.x] + tscan[i] - count[i];
}

// scatter: emit sorted-order edge permutation + sorted dst/col arrays
__global__ void scatter_kernel(const int* __restrict__ rowI,
                               const int* __restrict__ colI,
                               int* __restrict__ cursor,
                               int* __restrict__ eperm, int* __restrict__ dsts,
                               int* __restrict__ cols) {
  int e = blockIdx.x * 256 + threadIdx.x;
  if (e < N_EDGES) {
    const int r = rowI[e];
    const int p = atomicAdd(&cursor[r], 1);
    eperm[p] = e;
    dsts[p] = r;
    cols[p] = colI[e];
  }
}

// ---------------------------------------------------------------------------
// Fused pass: filter + modulate + segmented reduce, sorted edge order.
//   SORTED=true : edges pre-sorted by dst; ~5 atomic flushes/thread/tile
//   SORTED=false: natural order fallback (more atomics, still correct)
// LDS (34816 B union pool):
//   [0      ..17408) sHv  (staged h rows)   -- overlapped by sT after hv read
//   [17408  ..26624) sRbf
//   [26624  ..26880) sAux (sorted dst per row)
// ---------------------------------------------------------------------------
template <bool SORTED>
__global__ __launch_bounds__(256, 4) void edge_fused_kernel(
    const int* __restrict__ eperm, const float* __restrict__ rbf,
    const float* __restrict__ W1, const float* __restrict__ b1,
    const float* __restrict__ W2, const float* __restrict__ b2,
    const unsigned short* __restrict__ hbf, const int* __restrict__ dsts,
    const int* __restrict__ cols, float* __restrict__ outp) {
  __shared__ __align__(16) char pool[IN_CH * W2_STR * 2];  // 34816 B

  unsigned short* sHv = (unsigned short*)pool;                            // 17408
  unsigned short* sT = (unsigned short*)pool;                             // overlap
  unsigned short* sRbf = (unsigned short*)(pool + TILE_M * HV_STR * 2);   // 9216
  int* sAux = (int*)(pool + TILE_M * HV_STR * 2 + TILE_M * RBF_STR * 2);  // 256

  const int t = threadIdx.x;
  const int lane = t & 63;
  const int l31 = lane & 31;
  const int lhalf = lane >> 5;
  const int wv = t >> 6;
  const int nbase = wv * 32 + l31;

  // ---- weight fragments (pool reused twice) ----
  {
    unsigned short* sW1T = (unsigned short*)pool;
    const int k = t >> 2;
    const int c0 = (t & 3) * 32;
#pragma unroll
    for (int i = 0; i < 8; ++i) {
      float4 v = *(const float4*)(W1 + k * OUT_CH + c0 + 4 * i);
      sW1T[(c0 + 4 * i + 0) * W1_STR + k] = f2bf(v.x);
      sW1T[(c0 + 4 * i + 1) * W1_STR + k] = f2bf(v.y);
      sW1T[(c0 + 4 * i + 2) * W1_STR + k] = f2bf(v.z);
      sW1T[(c0 + 4 * i + 3) * W1_STR + k] = f2bf(v.w);
    }
  }
  __syncthreads();
  bf16x8 B1[4];
  {
    const unsigned short* sW1T = (const unsigned short*)pool;
#pragma unroll
    for (int kk = 0; kk < 4; ++kk)
      B1[kk] = *(const bf16x8*)&sW1T[nbase * W1_STR + kk * 16 + lhalf * 8];
  }
  __syncthreads();
  {
    unsigned short* sW2T = (unsigned short*)pool;
    const int k2 = t >> 1;
    const int d0 = (t & 1) * 64;
#pragma unroll
    for (int i = 0; i < 16; ++i) {
      float4 v = *(const float4*)(W2 + k2 * OUT_CH + d0 + 4 * i);
      sW2T[(d0 + 4 * i + 0) * W2_STR + k2] = f2bf(v.x);
      sW2T[(d0 + 4 * i + 1) * W2_STR + k2] = f2bf(v.y);
      sW2T[(d0 + 4 * i + 2) * W2_STR + k2] = f2bf(v.z);
      sW2T[(d0 + 4 * i + 3) * W2_STR + k2] = f2bf(v.w);
    }
  }
  __syncthreads();
  bf16x8 B2[8];
  {
    const unsigned short* sW2T = (const unsigned short*)pool;
#pragma unroll
    for (int kk = 0; kk < 8; ++kk)
      B2[kk] = *(const bf16x8*)&sW2T[nbase * W2_STR + kk * 16 + lhalf * 8];
  }
  const float b1v = b1[nbase];
  const float b2v = b2[nbase];

  for (int tile = blockIdx.x; tile < NTILES; tile += gridDim.x) {
    const int ebase = tile * TILE_M;
    __syncthreads();  // (a) prev GEMM2/sAux reads complete before restage

    // ---- stage rbf (bf16, gathered via eperm) + h rows -> sHv + dst ----
    {
      const int m = t >> 2;
      const int ep = SORTED ? eperm[ebase + m] : (ebase + m);
      const int kq = (t & 3) * 16;
      const float* src = rbf + (size_t)ep * NUM_RBF + kq;
#pragma unroll
      for (int i = 0; i < 4; ++i) {
        float4 v = *(const float4*)(src + 4 * i);
        ushort4 p;
        p.x = f2bf(v.x); p.y = f2bf(v.y); p.z = f2bf(v.z); p.w = f2bf(v.w);
        *(ushort4*)&sRbf[m * RBF_STR + kq + 4 * i] = p;
      }
      // 64 rows x 256B of hbf, 16B per thread-chunk, 4 chunks/thread
#pragma unroll
      for (int i = 0; i < 4; ++i) {
        const int chunk = t + 256 * i;
        const int row = chunk >> 4;
        const int c8 = (chunk & 15) * 8;  // ushort offset within row
        const int col = cols[ebase + row];
        *(uint4*)&sHv[row * HV_STR + c8] =
            *(const uint4*)(hbf + (size_t)col * OUT_CH + c8);
      }
      if (t < TILE_M) sAux[t] = dsts[ebase + t];
    }
    __syncthreads();  // (b)

    // ---- h values from LDS (read BEFORE sT overwrites sHv) ----
    float hv[2][16];
#pragma unroll
    for (int mt = 0; mt < 2; ++mt)
#pragma unroll
      for (int r = 0; r < 16; ++r) {
        const int rowm = mt * 32 + (r & 3) + 8 * (r >> 2) + 4 * lhalf;
        hv[mt][r] = bf2f(sHv[rowm * HV_STR + nbase]);
      }
    __syncthreads();  // (b2) sHv reads done; sT may overwrite

    // ---- GEMM1: sT = bf16(relu(rbf @ W1 + b1)) ----
#pragma unroll
    for (int mt = 0; mt < 2; ++mt) {
      f32x16 acc = {0.f, 0.f, 0.f, 0.f, 0.f, 0.f, 0.f, 0.f,
                    0.f, 0.f, 0.f, 0.f, 0.f, 0.f, 0.f, 0.f};
#pragma unroll
      for (int kk = 0; kk < 4; ++kk) {
        bf16x8 A = *(const bf16x8*)&sRbf[(mt * 32 + l31) * RBF_STR + kk * 16 + lhalf * 8];
        acc = __builtin_amdgcn_mfma_f32_32x32x16_bf16(A, B1[kk], acc, 0, 0, 0);
      }
#pragma unroll
      for (int r = 0; r < 16; ++r) {
        const int rowm = (r & 3) + 8 * (r >> 2) + 4 * lhalf;
        float v = acc[r] + b1v;
        v = v > 0.f ? v : 0.f;
        sT[(mt * 32 + rowm) * T_STR + nbase] = f2bf(v);
      }
    }
    __syncthreads();  // (c)

    // ---- GEMM2 + modulate + in-register segmented reduce ----
    // Thread owns rows {mt*32 + 8q + 4*lhalf + j} in increasing order; rows
    // are dst-sorted, so a serial scan with atomic flush per segment works.
    float sum = 0.f;
    int curd = -1;
#pragma unroll
    for (int mt = 0; mt < 2; ++mt) {
      f32x16 acc = {0.f, 0.f, 0.f, 0.f, 0.f, 0.f, 0.f, 0.f,
                    0.f, 0.f, 0.f, 0.f, 0.f, 0.f, 0.f, 0.f};
#pragma unroll
      for (int kk = 0; kk < 8; ++kk) {
        bf16x8 A = *(const bf16x8*)&sT[(mt * 32 + l31) * T_STR + kk * 16 + lhalf * 8];
        acc = __builtin_amdgcn_mfma_f32_32x32x16_bf16(A, B2[kk], acc, 0, 0, 0);
      }
#pragma unroll
      for (int r = 0; r < 16; ++r) {
        const int rowm = mt * 32 + (r & 3) + 8 * (r >> 2) + 4 * lhalf;
        const float m = hv[mt][r] * (acc[r] + b2v);
        const int d = sAux[rowm];
        if (d != curd) {
          if (curd >= 0) atomicAdd(&outp[(size_t)curd * OUT_CH + nbase], sum);
          curd = d;
          sum = m;
        } else {
          sum += m;
        }
      }
    }
    atomicAdd(&outp[(size_t)curd * OUT_CH + nbase], sum);
  }
}

// ---------------------------------------------------------------------------
extern "C" void kernel_launch(void* const* d_in, const int* in_sizes, int n_in,
                              void* d_out, int out_size, void* d_ws, size_t ws_size,
                              hipStream_t stream) {
  const float* x    = (const float*)d_in[0];
  const int*   eidx = (const int*)d_in[1];
  const float* rbf  = (const float*)d_in[2];
  const float* W1   = (const float*)d_in[3];
  const float* b1   = (const float*)d_in[4];
  const float* W2   = (const float*)d_in[5];
  const float* b2   = (const float*)d_in[6];
  const float* Wl   = (const float*)d_in[7];
  const float* bl   = (const float*)d_in[8];
  float* out = (float*)d_out;

  char* ws = (char*)d_ws;
  const size_t HBF_B = (size_t)N_NODES * OUT_CH * 2;  // 10,240,000
  const size_t EP_B = (size_t)N_EDGES * 4;            //  2,560,000 (x3)
  const size_t CNT_B = (size_t)N_NODES * 4;           //    160,000 (x3)
  const size_t BS_B = 4 * 256;
  const size_t need = HBF_B + 3 * EP_B + 3 * CNT_B + 2 * BS_B + 64;

  size_t off = 0;
  unsigned short* hbf = (unsigned short*)(ws + off); off += HBF_B;
  int* eperm  = (int*)(ws + off); off += EP_B;
  int* dsts   = (int*)(ws + off); off += EP_B;
  int* cols   = (int*)(ws + off); off += EP_B;
  int* count  = (int*)(ws + off); off += CNT_B;
  int* cursor = (int*)(ws + off); off += CNT_B;
  int* tscan  = (int*)(ws + off); off += CNT_B;
  int* bsum   = (int*)(ws + off); off += BS_B;
  int* boff   = (int*)(ws + off); off += BS_B;

  const int* rowI = eidx;
  const int* colI = eidx + N_EDGES;

  hipMemsetAsync(out, 0, (size_t)N_NODES * OUT_CH * sizeof(float), stream);
  node_linear_mfma<<<N_NODES / TILE_M, 256, 0, stream>>>(x, Wl, bl, hbf);

  if (ws_size >= need) {
    hipMemsetAsync(count, 0, CNT_B, stream);
    hist_kernel<<<(N_EDGES + 255) / 256, 256, 0, stream>>>(rowI, count);
    scan1_kernel<<<NSCB, 256, 0, stream>>>(count, tscan, bsum);
    scan2_kernel<<<1, 256, 0, stream>>>(bsum, boff);
    scan3_kernel<<<NSCB, 256, 0, stream>>>(count, tscan, boff, cursor);
    scatter_kernel<<<(N_EDGES + 255) / 256, 256, 0, stream>>>(
        rowI, colI, cursor, eperm, dsts, cols);
    edge_fused_kernel<true><<<EDGE_GRID, 256, 0, stream>>>(
        eperm, rbf, W1, b1, W2, b2, hbf, dsts, cols, out);
  } else {
    edge_fused_kernel<false><<<EDGE_GRID, 256, 0, stream>>>(
        nullptr, rbf, W1, b1, W2, b2, hbf, rowI, colI, out);
  }
}